// Round 1
// baseline (575.212 us; speedup 1.0000x reference)
//
#include <hip/hip_runtime.h>
#include <math.h>

#define Bn 2048
#define Dd 128
#define Cc 50000

#define ARC_SCALE 64.0f
#define COS_Mf 0.8775825618903728f
#define SIN_Mf 0.479425538604203f
#define THf (-0.8775825618903728f)
#define MMf 0.2397127693021015f

#define CSPL 16
#define CPS 3125      // 50000/16
#define ATILES 49     // ceil(3125/64)
#define TSPL 8
#define TTILES 4      // 2048/8/64

// ---------------- row normalization (emb and W) ----------------
__global__ void norm_rows(const float* __restrict__ in, float* __restrict__ out,
                          float* __restrict__ sq, int nrows) {
    int wid = threadIdx.x >> 6;
    int lane = threadIdx.x & 63;
    int row = blockIdx.x * 4 + wid;
    if (row >= nrows) return;
    const float* p = in + (size_t)row * Dd;
    float e0 = p[lane], e1 = p[lane + 64];
    float ss = e0 * e0 + e1 * e1;
    #pragma unroll
    for (int o = 32; o > 0; o >>= 1) ss += __shfl_xor(ss, o);
    float rn = rsqrtf(ss);
    float* q = out + (size_t)row * Dd;
    q[lane] = e0 * rn;
    q[lane + 64] = e1 * rn;
    if (sq != nullptr && lane == 0) sq[row] = ss;
}

// ---------------- fused cosine-GEMM + online logsumexp partials ----------------
__launch_bounds__(256, 2)
__global__ void arc_main(const float* __restrict__ en, const float* __restrict__ wn,
                         float* __restrict__ pm, float* __restrict__ ps,
                         float* __restrict__ px) {
    __shared__ float se[64][132];
    __shared__ float sw[64][132];
    __shared__ float red[64][16][3];
    const int t = threadIdx.x;
    const int tx = t & 15, ty = t >> 4;
    const int r0 = blockIdx.x * 64;
    const int split = blockIdx.y;
    const int cbeg = split * CPS;
    const int cend = cbeg + CPS;

    // stage 64 emb_n rows once
    #pragma unroll
    for (int j = 0; j < 8; ++j) {
        int f = t + j * 256;          // float4 index 0..2047
        int r = f >> 5;               // 0..63
        int kk = (f & 31) << 2;
        const float4 v = *reinterpret_cast<const float4*>(en + (size_t)(r0 + r) * Dd + kk);
        se[r][kk] = v.x; se[r][kk + 1] = v.y; se[r][kk + 2] = v.z; se[r][kk + 3] = v.w;
    }

    float lm[4], ls[4], lx[4];
    #pragma unroll
    for (int i = 0; i < 4; ++i) { lm[i] = -1e30f; ls[i] = 0.f; lx[i] = 0.f; }

    for (int tile = 0; tile < ATILES; ++tile) {
        const int c0 = cbeg + tile * 64;
        __syncthreads();
        #pragma unroll
        for (int j = 0; j < 8; ++j) {
            int f = t + j * 256;
            int r = f >> 5;
            int kk = (f & 31) << 2;
            int c = c0 + r;
            float4 v = make_float4(0.f, 0.f, 0.f, 0.f);
            if (c < Cc) v = *reinterpret_cast<const float4*>(wn + (size_t)c * Dd + kk);
            sw[r][kk] = v.x; sw[r][kk + 1] = v.y; sw[r][kk + 2] = v.z; sw[r][kk + 3] = v.w;
        }
        __syncthreads();

        float acc[4][4];
        #pragma unroll
        for (int i = 0; i < 4; ++i)
            #pragma unroll
            for (int j = 0; j < 4; ++j) acc[i][j] = 0.f;

        for (int k = 0; k < Dd; k += 4) {
            float4 a[4], b[4];
            #pragma unroll
            for (int i = 0; i < 4; ++i)
                a[i] = *reinterpret_cast<const float4*>(&se[ty + 16 * i][k]);
            #pragma unroll
            for (int j = 0; j < 4; ++j)
                b[j] = *reinterpret_cast<const float4*>(&sw[tx + 16 * j][k]);
            #pragma unroll
            for (int i = 0; i < 4; ++i)
                #pragma unroll
                for (int j = 0; j < 4; ++j)
                    acc[i][j] += a[i].x * b[j].x + a[i].y * b[j].y +
                                 a[i].z * b[j].z + a[i].w * b[j].w;
        }

        // online lse + plain sum over this tile's classes
        #pragma unroll
        for (int i = 0; i < 4; ++i) {
            #pragma unroll
            for (int j = 0; j < 4; ++j) {
                int c = c0 + tx + 16 * j;
                if (c < cend) {
                    float x = ARC_SCALE * acc[i][j];
                    float nm = fmaxf(lm[i], x);
                    ls[i] = ls[i] * __expf(lm[i] - nm) + __expf(x - nm);
                    lm[i] = nm;
                    lx[i] += x;
                }
            }
        }
    }

    __syncthreads();
    #pragma unroll
    for (int i = 0; i < 4; ++i) {
        red[ty + 16 * i][tx][0] = lm[i];
        red[ty + 16 * i][tx][1] = ls[i];
        red[ty + 16 * i][tx][2] = lx[i];
    }
    __syncthreads();
    if (t < 64) {
        float m = -1e30f, s = 0.f, x = 0.f;
        for (int u = 0; u < 16; ++u) {
            float um = red[t][u][0], us = red[t][u][1];
            float nm = fmaxf(m, um);
            s = s * __expf(m - nm) + us * __expf(um - nm);
            m = nm;
            x += red[t][u][2];
        }
        int row = r0 + t;
        pm[row * CSPL + split] = m;
        ps[row * CSPL + split] = s;
        px[row * CSPL + split] = x;
    }
}

// ---------------- per-row label logit (base & phi-modified) ----------------
__global__ void target_k(const float* __restrict__ en, const float* __restrict__ wn,
                         const int* __restrict__ lab, float* __restrict__ bx,
                         float* __restrict__ tg) {
    int wid = threadIdx.x >> 6, lane = threadIdx.x & 63;
    int row = blockIdx.x * 4 + wid;
    if (row >= Bn) return;
    int l = lab[row];
    const float* e = en + (size_t)row * Dd;
    const float* w = wn + (size_t)l * Dd;
    float s = e[lane] * w[lane] + e[lane + 64] * w[lane + 64];
    #pragma unroll
    for (int o = 32; o > 0; o >>= 1) s += __shfl_xor(s, o);
    if (lane == 0) {
        float c = s;
        float s2 = fminf(fmaxf(1.f - c * c, 0.f), 1.f);
        float sine = sqrtf(s2);
        float phi = c * COS_Mf - sine * SIN_Mf;
        phi = (c > THf) ? phi : (c - MMf);
        bx[row] = ARC_SCALE * c;
        tg[row] = ARC_SCALE * phi;
    }
}

// ---------------- batch-hard triplet partials ----------------
__launch_bounds__(256, 2)
__global__ void trip_k(const float* __restrict__ emb, const float* __restrict__ sqn,
                       const int* __restrict__ lab,
                       float* __restrict__ hp, float* __restrict__ hn,
                       float* __restrict__ cnt) {
    __shared__ float se[64][132];
    __shared__ float sc[64][132];
    __shared__ float csq[64];
    __shared__ int clb[64];
    __shared__ float red[64][16][3];
    const int t = threadIdx.x;
    const int tx = t & 15, ty = t >> 4;
    const int r0 = blockIdx.x * 64;
    const int split = blockIdx.y;

    #pragma unroll
    for (int j = 0; j < 8; ++j) {
        int f = t + j * 256; int r = f >> 5; int kk = (f & 31) << 2;
        const float4 v = *reinterpret_cast<const float4*>(emb + (size_t)(r0 + r) * Dd + kk);
        se[r][kk] = v.x; se[r][kk + 1] = v.y; se[r][kk + 2] = v.z; se[r][kk + 3] = v.w;
    }
    float rsq[4]; int rlb[4];
    #pragma unroll
    for (int i = 0; i < 4; ++i) { rsq[i] = sqn[r0 + ty + 16 * i]; rlb[i] = lab[r0 + ty + 16 * i]; }
    float vhp[4] = {0.f, 0.f, 0.f, 0.f};
    float vhn[4] = {1e30f, 1e30f, 1e30f, 1e30f};
    float vct[4] = {0.f, 0.f, 0.f, 0.f};

    for (int tile = 0; tile < TTILES; ++tile) {
        const int c0 = split * (TTILES * 64) + tile * 64;
        __syncthreads();
        #pragma unroll
        for (int j = 0; j < 8; ++j) {
            int f = t + j * 256; int r = f >> 5; int kk = (f & 31) << 2;
            const float4 v = *reinterpret_cast<const float4*>(emb + (size_t)(c0 + r) * Dd + kk);
            sc[r][kk] = v.x; sc[r][kk + 1] = v.y; sc[r][kk + 2] = v.z; sc[r][kk + 3] = v.w;
        }
        if (t < 64) { csq[t] = sqn[c0 + t]; clb[t] = lab[c0 + t]; }
        __syncthreads();

        float acc[4][4];
        #pragma unroll
        for (int i = 0; i < 4; ++i)
            #pragma unroll
            for (int j = 0; j < 4; ++j) acc[i][j] = 0.f;

        for (int k = 0; k < Dd; k += 4) {
            float4 a[4], b[4];
            #pragma unroll
            for (int i = 0; i < 4; ++i)
                a[i] = *reinterpret_cast<const float4*>(&se[ty + 16 * i][k]);
            #pragma unroll
            for (int j = 0; j < 4; ++j)
                b[j] = *reinterpret_cast<const float4*>(&sc[tx + 16 * j][k]);
            #pragma unroll
            for (int i = 0; i < 4; ++i)
                #pragma unroll
                for (int j = 0; j < 4; ++j)
                    acc[i][j] += a[i].x * b[j].x + a[i].y * b[j].y +
                                 a[i].z * b[j].z + a[i].w * b[j].w;
        }

        #pragma unroll
        for (int i = 0; i < 4; ++i) {
            int ri = r0 + ty + 16 * i;
            #pragma unroll
            for (int j = 0; j < 4; ++j) {
                int cj = c0 + tx + 16 * j;
                float d2 = rsq[i] + csq[tx + 16 * j] - 2.f * acc[i][j];
                float dist = sqrtf(fmaxf(d2, 0.f) + 1e-16f);
                bool same = (rlb[i] == clb[tx + 16 * j]);
                bool self = (ri == cj);
                if (same && !self) { vhp[i] = fmaxf(vhp[i], dist); vct[i] += 1.f; }
                if (!same) vhn[i] = fminf(vhn[i], dist);
            }
        }
    }

    __syncthreads();
    #pragma unroll
    for (int i = 0; i < 4; ++i) {
        red[ty + 16 * i][tx][0] = vhp[i];
        red[ty + 16 * i][tx][1] = vhn[i];
        red[ty + 16 * i][tx][2] = vct[i];
    }
    __syncthreads();
    if (t < 64) {
        float a = 0.f, b = 1e30f, c = 0.f;
        for (int u = 0; u < 16; ++u) {
            a = fmaxf(a, red[t][u][0]);
            b = fminf(b, red[t][u][1]);
            c += red[t][u][2];
        }
        hp[(r0 + t) * TSPL + split] = a;
        hn[(r0 + t) * TSPL + split] = b;
        cnt[(r0 + t) * TSPL + split] = c;
    }
}

// ---------------- final merge -> scalar loss ----------------
__launch_bounds__(256)
__global__ void final_k(const float* __restrict__ pm, const float* __restrict__ ps,
                        const float* __restrict__ px, const float* __restrict__ bx,
                        const float* __restrict__ tg, const float* __restrict__ hp,
                        const float* __restrict__ hn, const float* __restrict__ cnt,
                        float* __restrict__ out) {
    __shared__ float sarc[4], stri[4], sval[4];
    float arcs = 0.f, tris = 0.f, vals = 0.f;
    for (int r = threadIdx.x; r < Bn; r += 256) {
        float m = -1e30f, s = 0.f, xs = 0.f;
        for (int u = 0; u < CSPL; ++u) {
            float um = pm[r * CSPL + u], us = ps[r * CSPL + u];
            float nm = fmaxf(m, um);
            s = s * __expf(m - nm) + us * __expf(um - nm);
            m = nm;
            xs += px[r * CSPL + u];
        }
        // replace label column's plain logit with phi-modified logit
        float base = bx[r], targ = tg[r];
        s += __expf(targ - m) - __expf(base - m);
        xs += targ - base;
        float lse = m + logf(s);
        float nll = lse - targ;
        float smooth = lse - xs / (float)Cc;
        arcs += 0.9f * nll + 0.1f * smooth;

        float a = 0.f, b = 1e30f, c = 0.f;
        for (int u = 0; u < TSPL; ++u) {
            a = fmaxf(a, hp[r * TSPL + u]);
            b = fminf(b, hn[r * TSPL + u]);
            c += cnt[r * TSPL + u];
        }
        float tl = fmaxf(a - b + 0.3f, 0.f);
        if (c > 0.f) { tris += tl; vals += 1.f; }
    }
    #pragma unroll
    for (int o = 32; o > 0; o >>= 1) {
        arcs += __shfl_xor(arcs, o);
        tris += __shfl_xor(tris, o);
        vals += __shfl_xor(vals, o);
    }
    int wid = threadIdx.x >> 6, lane = threadIdx.x & 63;
    if (lane == 0) { sarc[wid] = arcs; stri[wid] = tris; sval[wid] = vals; }
    __syncthreads();
    if (threadIdx.x == 0) {
        float A = sarc[0] + sarc[1] + sarc[2] + sarc[3];
        float T = stri[0] + stri[1] + stri[2] + stri[3];
        float V = sval[0] + sval[1] + sval[2] + sval[3];
        float tri = (V > 0.f) ? (T / fmaxf(V, 1.f)) : 0.f;
        out[0] = A / (float)Bn + 0.5f * tri;
    }
}

extern "C" void kernel_launch(void* const* d_in, const int* in_sizes, int n_in,
                              void* d_out, int out_size, void* d_ws, size_t ws_size,
                              hipStream_t stream) {
    const float* emb = (const float*)d_in[0];
    const float* W = (const float*)d_in[1];
    const int* lab = (const int*)d_in[2];
    float* out = (float*)d_out;

    float* ws = (float*)d_ws;
    float* embn = ws;
    float* sqn = embn + (size_t)Bn * Dd;
    float* wn = sqn + Bn;
    float* pm = wn + (size_t)Cc * Dd;
    float* ps = pm + (size_t)Bn * CSPL;
    float* px = ps + (size_t)Bn * CSPL;
    float* bx = px + (size_t)Bn * CSPL;
    float* tg = bx + Bn;
    float* hp = tg + Bn;
    float* hn = hp + (size_t)Bn * TSPL;
    float* ct = hn + (size_t)Bn * TSPL;

    norm_rows<<<Bn / 4, 256, 0, stream>>>(emb, embn, sqn, Bn);
    norm_rows<<<(Cc + 3) / 4, 256, 0, stream>>>(W, wn, nullptr, Cc);
    arc_main<<<dim3(Bn / 64, CSPL), 256, 0, stream>>>(embn, wn, pm, ps, px);
    target_k<<<Bn / 4, 256, 0, stream>>>(embn, wn, lab, bx, tg);
    trip_k<<<dim3(Bn / 64, TSPL), 256, 0, stream>>>(emb, sqn, lab, hp, hn, ct);
    final_k<<<1, 256, 0, stream>>>(pm, ps, px, bx, tg, hp, hn, ct, out);
}

// Round 2
// 105.298 us; speedup vs baseline: 5.4627x; 5.4627x over previous
//
#include <hip/hip_runtime.h>
#include <math.h>

#define Bn 2048
#define Dd 128
#define Cc 50000
#define NSPL 32
#define NTILE 782   // ceil(50000/64)

#define COS_Mf 0.8775825618903728f
#define SIN_Mf 0.479425538604203f
#define THf (-0.8775825618903728f)
#define MMf 0.2397127693021015f

#define TSPL 8
#define TTILES 4      // 2048/8/64

typedef __attribute__((ext_vector_type(8))) short short8;
typedef __attribute__((ext_vector_type(4))) float f32x4;

__device__ __forceinline__ unsigned short f2bf(float f) {
    unsigned int u = __float_as_uint(f);
    u += 0x7fffu + ((u >> 16) & 1u);
    return (unsigned short)(u >> 16);
}
__device__ __forceinline__ float bf2f(unsigned short h) {
    return __uint_as_float(((unsigned int)h) << 16);
}

// ---------------- row normalization -> bf16 (emb and W) ----------------
__global__ void norm_rows(const float* __restrict__ in, unsigned short* __restrict__ out,
                          float* __restrict__ sq, int nrows) {
    int wid = threadIdx.x >> 6;
    int lane = threadIdx.x & 63;
    int row = blockIdx.x * 4 + wid;
    if (row >= nrows) return;
    const float* p = in + (size_t)row * Dd;
    float e0 = p[lane], e1 = p[lane + 64];
    float ss = e0 * e0 + e1 * e1;
    #pragma unroll
    for (int o = 32; o > 0; o >>= 1) ss += __shfl_xor(ss, o);
    float rn = rsqrtf(ss);
    unsigned short* q = out + (size_t)row * Dd;
    q[lane] = f2bf(e0 * rn);
    q[lane + 64] = f2bf(e1 * rn);
    if (sq != nullptr && lane == 0) sq[row] = ss;
}

// ---------------- fused bf16-MFMA cosine-GEMM + fixed-max softmax partials ----------------
// grid: (16 row-blocks of 128, NSPL col-splits). block: 256 thr = 4 waves.
// wave w: rows (w&1)*64..+64, cols (w>>1)*32..+32 of each 64-col tile.
__launch_bounds__(256, 2)
__global__ void arc_main(const unsigned short* __restrict__ en,
                         const unsigned short* __restrict__ wn,
                         float* __restrict__ ps, float* __restrict__ xp) {
    __shared__ unsigned short swb[2][8192];   // 2 x 16KB: [col 0..63][k 0..127] bf16, XOR-swizzled
    __shared__ float sred[4][64];
    __shared__ float xred[4];
    const int t = threadIdx.x;
    const int w = t >> 6, l = t & 63;
    const int r0 = blockIdx.x * 128;
    const int split = blockIdx.y;
    const int rowbase = r0 + (w & 1) * 64;
    const int colb = (w >> 1) * 32;

    // A panel (64 rows x K=128) in registers: frag layout row=l&15, k=(l>>4)*8..+8
    short8 afrag[4][4];
    #pragma unroll
    for (int sm = 0; sm < 4; ++sm) {
        #pragma unroll
        for (int kc = 0; kc < 4; ++kc) {
            int row = rowbase + sm * 16 + (l & 15);
            int k0 = kc * 32 + (l >> 4) * 8;
            afrag[sm][kc] = *reinterpret_cast<const short8*>(en + (size_t)row * Dd + k0);
        }
    }

    float sacc[4][4];
    #pragma unroll
    for (int sm = 0; sm < 4; ++sm)
        #pragma unroll
        for (int r = 0; r < 4; ++r) sacc[sm][r] = 0.f;
    float xacc = 0.f;

    const int ntm = (NTILE - 1 - split) / NSPL + 1;

    auto STAGE = [&](int buf, int idx) {
        int tl = split + idx * NSPL;
        if (tl > NTILE - 1) tl = NTILE - 1;
        int c0t = tl * 64;
        #pragma unroll
        for (int j = 0; j < 4; ++j) {
            // linear LDS dest; source pre-swizzled so reads can apply the same XOR
            int col = (w * 4 + j) * 4 + (l >> 4);
            int kb = ((l & 15) * 16) ^ ((col & 7) << 4);
            int c = c0t + col;
            if (c > Cc - 1) c = Cc - 1;
            const unsigned short* src = wn + ((size_t)c << 7) + (kb >> 1);
            __builtin_amdgcn_global_load_lds(
                (const __attribute__((address_space(1))) void*)src,
                (__attribute__((address_space(3))) void*)(&swb[buf][(w * 4 + j) * 512]),
                16, 0, 0);
        }
    };

    STAGE(0, 0);
    for (int i = 0; i < ntm; ++i) {
        __syncthreads();              // drains vmcnt: current buf staged & visible
        STAGE((i & 1) ^ 1, i + 1);    // prefetch next tile (overlaps compute)
        const unsigned short* bb = swb[i & 1];
        const int c0t = (split + i * NSPL) * 64;

        f32x4 acc[4][2];
        #pragma unroll
        for (int sm = 0; sm < 4; ++sm)
            #pragma unroll
            for (int sn = 0; sn < 2; ++sn)
                acc[sm][sn] = (f32x4){0.f, 0.f, 0.f, 0.f};

        #pragma unroll
        for (int kc = 0; kc < 4; ++kc) {
            short8 bfr[2];
            #pragma unroll
            for (int sn = 0; sn < 2; ++sn) {
                int rcol = colb + sn * 16 + (l & 15);
                int rkb = (kc * 64 + (l >> 4) * 16) ^ ((rcol & 7) << 4);
                bfr[sn] = *reinterpret_cast<const short8*>(bb + rcol * 128 + (rkb >> 1));
            }
            #pragma unroll
            for (int sn = 0; sn < 2; ++sn)
                #pragma unroll
                for (int sm = 0; sm < 4; ++sm)
                    acc[sm][sn] = __builtin_amdgcn_mfma_f32_16x16x32_bf16(
                        afrag[sm][kc], bfr[sn], acc[sm][sn], 0, 0, 0);
        }

        // epilogue: s += exp(64c - 64), x += c ; col-validity uniform per sn (50000 % 16 == 0)
        #pragma unroll
        for (int sn = 0; sn < 2; ++sn) {
            if (c0t + colb + sn * 16 < Cc) {
                #pragma unroll
                for (int sm = 0; sm < 4; ++sm)
                    #pragma unroll
                    for (int r = 0; r < 4; ++r) {
                        float a = acc[sm][sn][r];
                        sacc[sm][r] += __expf(fmaf(a, 64.f, -64.f));
                        xacc += a;
                    }
            }
        }
    }

    // intra-wave reduce: sum over 16 col-lanes; C/D layout: col=l&15, row=(l>>4)*4+reg
    #pragma unroll
    for (int sm = 0; sm < 4; ++sm)
        #pragma unroll
        for (int r = 0; r < 4; ++r) {
            float v = sacc[sm][r];
            v += __shfl_xor(v, 1); v += __shfl_xor(v, 2);
            v += __shfl_xor(v, 4); v += __shfl_xor(v, 8);
            sacc[sm][r] = v;
        }
    float xv = xacc;
    #pragma unroll
    for (int o = 32; o > 0; o >>= 1) xv += __shfl_xor(xv, o);

    if ((l & 15) == 0) {
        int g = l >> 4;
        #pragma unroll
        for (int sm = 0; sm < 4; ++sm)
            #pragma unroll
            for (int r = 0; r < 4; ++r)
                sred[w][sm * 16 + g * 4 + r] = sacc[sm][r];
    }
    if (l == 0) xred[w] = xv;
    __syncthreads();
    if (t < 128) {
        float s = (t < 64) ? (sred[0][t] + sred[2][t]) : (sred[1][t - 64] + sred[3][t - 64]);
        ps[(size_t)(r0 + t) * NSPL + split] = s;
    }
    if (t == 0) xp[blockIdx.x * NSPL + split] = xred[0] + xred[1] + xred[2] + xred[3];
}

// ---------------- per-row label logit (bf16-consistent base & phi) ----------------
__global__ void target_k(const unsigned short* __restrict__ en,
                         const unsigned short* __restrict__ wn,
                         const int* __restrict__ lab, float* __restrict__ bx,
                         float* __restrict__ tg) {
    int wid = threadIdx.x >> 6, lane = threadIdx.x & 63;
    int row = blockIdx.x * 4 + wid;
    if (row >= Bn) return;
    int lb = lab[row];
    const unsigned short* e = en + (size_t)row * Dd;
    const unsigned short* wv = wn + (size_t)lb * Dd;
    float s = bf2f(e[lane]) * bf2f(wv[lane]) + bf2f(e[lane + 64]) * bf2f(wv[lane + 64]);
    #pragma unroll
    for (int o = 32; o > 0; o >>= 1) s += __shfl_xor(s, o);
    if (lane == 0) {
        float c = s;
        float s2 = fminf(fmaxf(1.f - c * c, 0.f), 1.f);
        float sine = sqrtf(s2);
        float phi = c * COS_Mf - sine * SIN_Mf;
        phi = (c > THf) ? phi : (c - MMf);
        bx[row] = 64.f * c;
        tg[row] = 64.f * phi;
    }
}

// ---------------- batch-hard triplet partials (fp32, unchanged) ----------------
__launch_bounds__(256, 2)
__global__ void trip_k(const float* __restrict__ emb, const float* __restrict__ sqn,
                       const int* __restrict__ lab,
                       float* __restrict__ hp, float* __restrict__ hn,
                       float* __restrict__ cnt) {
    __shared__ float se[64][132];
    __shared__ float sc[64][132];
    __shared__ float csq[64];
    __shared__ int clb[64];
    __shared__ float red[64][16][3];
    const int t = threadIdx.x;
    const int tx = t & 15, ty = t >> 4;
    const int r0 = blockIdx.x * 64;
    const int split = blockIdx.y;

    #pragma unroll
    for (int j = 0; j < 8; ++j) {
        int f = t + j * 256; int r = f >> 5; int kk = (f & 31) << 2;
        const float4 v = *reinterpret_cast<const float4*>(emb + (size_t)(r0 + r) * Dd + kk);
        se[r][kk] = v.x; se[r][kk + 1] = v.y; se[r][kk + 2] = v.z; se[r][kk + 3] = v.w;
    }
    float rsq[4]; int rlb[4];
    #pragma unroll
    for (int i = 0; i < 4; ++i) { rsq[i] = sqn[r0 + ty + 16 * i]; rlb[i] = lab[r0 + ty + 16 * i]; }
    float vhp[4] = {0.f, 0.f, 0.f, 0.f};
    float vhn[4] = {1e30f, 1e30f, 1e30f, 1e30f};
    float vct[4] = {0.f, 0.f, 0.f, 0.f};

    for (int tile = 0; tile < TTILES; ++tile) {
        const int c0 = split * (TTILES * 64) + tile * 64;
        __syncthreads();
        #pragma unroll
        for (int j = 0; j < 8; ++j) {
            int f = t + j * 256; int r = f >> 5; int kk = (f & 31) << 2;
            const float4 v = *reinterpret_cast<const float4*>(emb + (size_t)(c0 + r) * Dd + kk);
            sc[r][kk] = v.x; sc[r][kk + 1] = v.y; sc[r][kk + 2] = v.z; sc[r][kk + 3] = v.w;
        }
        if (t < 64) { csq[t] = sqn[c0 + t]; clb[t] = lab[c0 + t]; }
        __syncthreads();

        float acc[4][4];
        #pragma unroll
        for (int i = 0; i < 4; ++i)
            #pragma unroll
            for (int j = 0; j < 4; ++j) acc[i][j] = 0.f;

        for (int k = 0; k < Dd; k += 4) {
            float4 a[4], b[4];
            #pragma unroll
            for (int i = 0; i < 4; ++i)
                a[i] = *reinterpret_cast<const float4*>(&se[ty + 16 * i][k]);
            #pragma unroll
            for (int j = 0; j < 4; ++j)
                b[j] = *reinterpret_cast<const float4*>(&sc[tx + 16 * j][k]);
            #pragma unroll
            for (int i = 0; i < 4; ++i)
                #pragma unroll
                for (int j = 0; j < 4; ++j)
                    acc[i][j] += a[i].x * b[j].x + a[i].y * b[j].y +
                                 a[i].z * b[j].z + a[i].w * b[j].w;
        }

        #pragma unroll
        for (int i = 0; i < 4; ++i) {
            int ri = r0 + ty + 16 * i;
            #pragma unroll
            for (int j = 0; j < 4; ++j) {
                int cj = c0 + tx + 16 * j;
                float d2 = rsq[i] + csq[tx + 16 * j] - 2.f * acc[i][j];
                float dist = sqrtf(fmaxf(d2, 0.f) + 1e-16f);
                bool same = (rlb[i] == clb[tx + 16 * j]);
                bool self = (ri == cj);
                if (same && !self) { vhp[i] = fmaxf(vhp[i], dist); vct[i] += 1.f; }
                if (!same) vhn[i] = fminf(vhn[i], dist);
            }
        }
    }

    __syncthreads();
    #pragma unroll
    for (int i = 0; i < 4; ++i) {
        red[ty + 16 * i][tx][0] = vhp[i];
        red[ty + 16 * i][tx][1] = vhn[i];
        red[ty + 16 * i][tx][2] = vct[i];
    }
    __syncthreads();
    if (t < 64) {
        float a = 0.f, b = 1e30f, c = 0.f;
        for (int u = 0; u < 16; ++u) {
            a = fmaxf(a, red[t][u][0]);
            b = fminf(b, red[t][u][1]);
            c += red[t][u][2];
        }
        hp[(r0 + t) * TSPL + split] = a;
        hn[(r0 + t) * TSPL + split] = b;
        cnt[(r0 + t) * TSPL + split] = c;
    }
}

// ---------------- final merge -> scalar loss ----------------
__launch_bounds__(256)
__global__ void final_k(const float* __restrict__ ps, const float* __restrict__ xp,
                        const float* __restrict__ bx, const float* __restrict__ tg,
                        const float* __restrict__ hp, const float* __restrict__ hn,
                        const float* __restrict__ cnt, float* __restrict__ out) {
    __shared__ float sA[4], sT[4], sV[4], sX[4];
    float arcs = 0.f, tris = 0.f, vals = 0.f, xs = 0.f;
    for (int r = threadIdx.x; r < Bn; r += 256) {
        float s = 0.f;
        for (int u = 0; u < NSPL; ++u) s += ps[(size_t)r * NSPL + u];
        float base = bx[r], targ = tg[r];
        s += __expf(targ - 64.f) - __expf(base - 64.f);   // swap label column to phi
        float lse = 64.f + logf(s);
        arcs += lse - 0.9f * targ - 0.1f * (targ - base) / (float)Cc;

        float a = 0.f, b = 1e30f, c = 0.f;
        for (int u = 0; u < TSPL; ++u) {
            a = fmaxf(a, hp[r * TSPL + u]);
            b = fminf(b, hn[r * TSPL + u]);
            c += cnt[r * TSPL + u];
        }
        float tl = fmaxf(a - b + 0.3f, 0.f);
        if (c > 0.f) { tris += tl; vals += 1.f; }
    }
    for (int i = threadIdx.x; i < 16 * NSPL; i += 256) xs += xp[i];
    #pragma unroll
    for (int o = 32; o > 0; o >>= 1) {
        arcs += __shfl_xor(arcs, o);
        tris += __shfl_xor(tris, o);
        vals += __shfl_xor(vals, o);
        xs   += __shfl_xor(xs, o);
    }
    int wid = threadIdx.x >> 6, lane = threadIdx.x & 63;
    if (lane == 0) { sA[wid] = arcs; sT[wid] = tris; sV[wid] = vals; sX[wid] = xs; }
    __syncthreads();
    if (threadIdx.x == 0) {
        float A = sA[0] + sA[1] + sA[2] + sA[3];
        float T = sT[0] + sT[1] + sT[2] + sT[3];
        float V = sV[0] + sV[1] + sV[2] + sV[3];
        float X = sX[0] + sX[1] + sX[2] + sX[3];
        float tri = (V > 0.f) ? (T / fmaxf(V, 1.f)) : 0.f;
        out[0] = (A - 0.1f * 64.f * X / (float)Cc) / (float)Bn + 0.5f * tri;
    }
}

extern "C" void kernel_launch(void* const* d_in, const int* in_sizes, int n_in,
                              void* d_out, int out_size, void* d_ws, size_t ws_size,
                              hipStream_t stream) {
    const float* emb = (const float*)d_in[0];
    const float* W = (const float*)d_in[1];
    const int* lab = (const int*)d_in[2];
    float* out = (float*)d_out;

    unsigned short* embn = (unsigned short*)d_ws;          // 2048*128 bf16
    unsigned short* wnb = embn + (size_t)Bn * Dd;          // 50000*128 bf16
    float* sqn = (float*)(wnb + (size_t)Cc * Dd);          // 2048
    float* ps = sqn + Bn;                                  // 2048*NSPL
    float* xp = ps + (size_t)Bn * NSPL;                    // 16*NSPL
    float* bx = xp + 16 * NSPL;                            // 2048
    float* tg = bx + Bn;                                   // 2048
    float* hp = tg + Bn;                                   // 2048*8
    float* hn = hp + (size_t)Bn * TSPL;                    // 2048*8
    float* ct = hn + (size_t)Bn * TSPL;                    // 2048*8

    norm_rows<<<Bn / 4, 256, 0, stream>>>(emb, embn, sqn, Bn);
    norm_rows<<<(Cc + 3) / 4, 256, 0, stream>>>(W, wnb, nullptr, Cc);
    arc_main<<<dim3(16, NSPL), 256, 0, stream>>>(embn, wnb, ps, xp);
    target_k<<<Bn / 4, 256, 0, stream>>>(embn, wnb, lab, bx, tg);
    trip_k<<<dim3(Bn / 64, TSPL), 256, 0, stream>>>(emb, sqn, lab, hp, hn, ct);
    final_k<<<1, 256, 0, stream>>>(ps, xp, bx, tg, hp, hn, ct, out);
}